// Round 1
// baseline (988.919 us; speedup 1.0000x reference)
//
#include <hip/hip_runtime.h>
#include <hip/hip_bf16.h>
#include <cstdint>
#include <cstddef>

#define TTOK   4096
#define DIM_   2048
#define INTER_ 1408
#define NEXP   16
#define SINTER_ 2816
#define BM 128
#define BN 128
#define BK 32
#define MAXROWS (TTOK*2 + NEXP*BM)      /* 10240 padded routed slots */
#define MAXMT   (TTOK*2/BM + NEXP)      /* 80 worst-case M tiles */

typedef unsigned short u16;
typedef __attribute__((ext_vector_type(8))) short short8;
typedef __attribute__((ext_vector_type(4))) float f32x4;

__device__ __forceinline__ u16 f2bf(float f) {
    unsigned u = __float_as_uint(f);
    u += 0x7FFFu + ((u >> 16) & 1u);     // RNE
    return (u16)(u >> 16);
}

__device__ __forceinline__ int4 pack8(float4 a, float4 b) {
    int4 r;
    r.x = (int)f2bf(a.x) | ((int)f2bf(a.y) << 16);
    r.y = (int)f2bf(a.z) | ((int)f2bf(a.w) << 16);
    r.z = (int)f2bf(b.x) | ((int)f2bf(b.y) << 16);
    r.w = (int)f2bf(b.z) | ((int)f2bf(b.w) << 16);
    return r;
}

// ---------------- small kernels ----------------

// misc layout (ints): [0..16) counts, [16..32) fill, [32..48) base,
//                     [48..128) tile_expert, [128..208) tile_row0
__global__ void init_kernel(int* perm_rt, float* pw_rt, int* perm_sh, int* misc) {
    int i = blockIdx.x * 256 + threadIdx.x;
    if (i < MAXROWS) { perm_rt[i] = -1; pw_rt[i] = 0.f; }
    if (i < TTOK)    perm_sh[i] = i;
    if (i < 32)      misc[i] = 0;
}

__global__ void convert_x_kernel(const float* __restrict__ x, u16* __restrict__ xb) {
    size_t i = (size_t)blockIdx.x * 256 + threadIdx.x;   // covers TTOK*DIM_/4
    float4 v = *(const float4*)(x + i * 4);
    uint2 o;
    o.x = (unsigned)f2bf(v.x) | ((unsigned)f2bf(v.y) << 16);
    o.y = (unsigned)f2bf(v.z) | ((unsigned)f2bf(v.w) << 16);
    *(uint2*)(xb + i * 4) = o;
}

__global__ void gate_kernel(const float* __restrict__ x, const float* __restrict__ gw,
                            int* __restrict__ topi, float* __restrict__ topw,
                            int* __restrict__ misc) {
    int t = blockIdx.x;
    int lane = threadIdx.x;
    const float* xr = x + (size_t)t * DIM_;
    float acc[NEXP];
#pragma unroll
    for (int e = 0; e < NEXP; e++) acc[e] = 0.f;
#pragma unroll
    for (int i = 0; i < 8; i++) {
        int k = i * 256 + lane * 4;
        float4 xv = *(const float4*)(xr + k);
#pragma unroll
        for (int e = 0; e < NEXP; e++) {
            float4 gv = *(const float4*)(gw + (size_t)e * DIM_ + k);
            acc[e] += xv.x * gv.x + xv.y * gv.y + xv.z * gv.z + xv.w * gv.w;
        }
    }
#pragma unroll
    for (int e = 0; e < NEXP; e++) {
        float v = acc[e];
        for (int off = 32; off > 0; off >>= 1) v += __shfl_down(v, off);
        acc[e] = v;   // lane 0 has the full dot
    }
    if (lane == 0) {
        float m = acc[0];
#pragma unroll
        for (int e = 1; e < NEXP; e++) m = fmaxf(m, acc[e]);
        float p[NEXP]; float s = 0.f;
#pragma unroll
        for (int e = 0; e < NEXP; e++) { p[e] = __expf(acc[e] - m); s += p[e]; }
        int i0 = 0; float v0 = p[0];
#pragma unroll
        for (int e = 1; e < NEXP; e++) if (p[e] > v0) { v0 = p[e]; i0 = e; }
        int i1 = -1; float v1 = -1.f;
#pragma unroll
        for (int e = 0; e < NEXP; e++) if (e != i0 && p[e] > v1) { v1 = p[e]; i1 = e; }
        float inv = 1.f / s;
        topi[2 * t] = i0; topi[2 * t + 1] = i1;
        topw[2 * t] = v0 * inv; topw[2 * t + 1] = v1 * inv;
        atomicAdd(&misc[i0], 1);
        atomicAdd(&misc[i1], 1);
    }
}

__global__ void scan_kernel(int* misc) {
    // single thread: padded per-expert bases + tile table
    int* counts = misc;
    int* base   = misc + 32;
    int* te     = misc + 48;
    int* tr     = misc + 128;
    int b = 0, tt = 0;
    for (int e = 0; e < NEXP; e++) {
        int c = counts[e];
        int nt = (c + BM - 1) >> 7;
        base[e] = b;
        for (int i = 0; i < nt; i++) { te[tt] = e; tr[tt] = b + i * BM; tt++; }
        b += nt * BM;
    }
    for (int i = tt; i < MAXMT; i++) te[i] = -1;
}

__global__ void scatter_kernel(const int* __restrict__ topi, const float* __restrict__ topw,
                               int* __restrict__ misc, int* __restrict__ perm,
                               float* __restrict__ pw) {
    int t = blockIdx.x * 256 + threadIdx.x;
    if (t >= TTOK) return;
    int* fill = misc + 16;
    int* base = misc + 32;
#pragma unroll
    for (int k = 0; k < 2; k++) {
        int e = topi[2 * t + k];
        int pos = base[e] + atomicAdd(&fill[e], 1);
        perm[pos] = t;
        pw[pos] = topw[2 * t + k];
    }
}

// ---------------- GEMM kernels ----------------
// All GEMMs: C[M,N] = A[M,K] @ B[N,K]^T ; A bf16, B f32 (converted while staging).
// 128x128 tile, BK=32, 4 waves (2x2 of 64x64), mfma_f32_16x16x32_bf16.
// Fragment layout: frag[j] = Mat[row = lane&15][k0 + (lane>>4)*8 + j]
// C layout: col = lane&15, row = (lane>>4)*4 + reg  (verified m89/m91)

template<bool GROUPED>
__global__ __launch_bounds__(256, 2) void gemm_h13_k(
    const u16* __restrict__ Xb,
    const float* __restrict__ W1b, const float* __restrict__ W3b,
    u16* __restrict__ H,
    const int* __restrict__ perm,
    const int* __restrict__ te, const int* __restrict__ tr,
    int N, int K)
{
    int e, slot0;
    if (GROUPED) {
        e = te[blockIdx.x];
        if (e < 0) return;
        slot0 = tr[blockIdx.x];
    } else { e = 0; slot0 = blockIdx.x * BM; }
    const int n0 = blockIdx.y * BN;
    const float* W1 = W1b + (size_t)e * N * K;
    const float* W3 = W3b + (size_t)e * N * K;

    __shared__ __align__(16) u16 As[BM * BK];
    __shared__ __align__(16) u16 B1s[BM * BK];
    __shared__ __align__(16) u16 B3s[BM * BK];

    const int tid = threadIdx.x;
    const int lane = tid & 63, wid = tid >> 6;
    const int wr = wid >> 1, wc = wid & 1;
    const int col = lane & 15, kg = lane >> 4;

    // A staging assignment: chunk c covers row c>>2, 8 bf16 at (c&3)*8
    const int r0 = tid >> 2, ko = (tid & 3) * 8;
    const int tok0 = perm[slot0 + r0];
    const int tok1 = perm[slot0 + r0 + 64];
    // B staging assignment: row tid>>1, 16 floats at (tid&1)*16
    const int rB = tid >> 1, hfB = (tid & 1) * 16;
    const float* p1 = W1 + (size_t)(n0 + rB) * K + hfB;
    const float* p3 = W3 + (size_t)(n0 + rB) * K + hfB;

    f32x4 acc1[4][4] = {};
    f32x4 acc3[4][4] = {};

    for (int k0 = 0; k0 < K; k0 += BK) {
        int4 va0 = make_int4(0, 0, 0, 0), va1 = make_int4(0, 0, 0, 0);
        if (tok0 >= 0) va0 = *(const int4*)(Xb + (size_t)tok0 * K + k0 + ko);
        if (tok1 >= 0) va1 = *(const int4*)(Xb + (size_t)tok1 * K + k0 + ko);
        *(int4*)(As + r0 * BK + ko) = va0;
        *(int4*)(As + (r0 + 64) * BK + ko) = va1;

        float4 a0 = *(const float4*)(p1 + k0);
        float4 a1 = *(const float4*)(p1 + k0 + 4);
        float4 a2 = *(const float4*)(p1 + k0 + 8);
        float4 a3 = *(const float4*)(p1 + k0 + 12);
        *(int4*)(B1s + rB * BK + hfB)     = pack8(a0, a1);
        *(int4*)(B1s + rB * BK + hfB + 8) = pack8(a2, a3);
        float4 c0 = *(const float4*)(p3 + k0);
        float4 c1 = *(const float4*)(p3 + k0 + 4);
        float4 c2 = *(const float4*)(p3 + k0 + 8);
        float4 c3 = *(const float4*)(p3 + k0 + 12);
        *(int4*)(B3s + rB * BK + hfB)     = pack8(c0, c1);
        *(int4*)(B3s + rB * BK + hfB + 8) = pack8(c2, c3);

        __syncthreads();

        short8 a[4];
#pragma unroll
        for (int mi = 0; mi < 4; mi++)
            a[mi] = *(const short8*)(As + (wr * 64 + mi * 16 + col) * BK + kg * 8);
#pragma unroll
        for (int ni = 0; ni < 4; ni++) {
            short8 v1 = *(const short8*)(B1s + (wc * 64 + ni * 16 + col) * BK + kg * 8);
            short8 v3 = *(const short8*)(B3s + (wc * 64 + ni * 16 + col) * BK + kg * 8);
#pragma unroll
            for (int mi = 0; mi < 4; mi++) {
                acc1[mi][ni] = __builtin_amdgcn_mfma_f32_16x16x32_bf16(a[mi], v1, acc1[mi][ni], 0, 0, 0);
                acc3[mi][ni] = __builtin_amdgcn_mfma_f32_16x16x32_bf16(a[mi], v3, acc3[mi][ni], 0, 0, 0);
            }
        }
        __syncthreads();
    }

    // epilogue: h = silu(acc1) * acc3, store bf16 (padding rows produce 0)
#pragma unroll
    for (int mi = 0; mi < 4; mi++) {
#pragma unroll
        for (int j = 0; j < 4; j++) {
            int row = slot0 + wr * 64 + mi * 16 + kg * 4 + j;
#pragma unroll
            for (int ni = 0; ni < 4; ni++) {
                float v1 = acc1[mi][ni][j];
                float v3 = acc3[mi][ni][j];
                float hv = v1 / (1.f + __expf(-v1)) * v3;
                int c = n0 + wc * 64 + ni * 16 + col;
                H[(size_t)row * N + c] = f2bf(hv);
            }
        }
    }
}

template<bool ATOMIC>
__global__ __launch_bounds__(256, 2) void gemm_out_k(
    const u16* __restrict__ Hm,
    const float* __restrict__ W2b,
    float* __restrict__ Out,
    const int* __restrict__ perm, const float* __restrict__ pw,
    const int* __restrict__ te, const int* __restrict__ tr,
    int K)
{
    int e, slot0;
    if (ATOMIC) {
        e = te[blockIdx.x];
        if (e < 0) return;
        slot0 = tr[blockIdx.x];
    } else { e = 0; slot0 = blockIdx.x * BM; }
    const int n0 = blockIdx.y * BN;
    const float* W2 = W2b + (size_t)e * DIM_ * K;

    __shared__ __align__(16) u16 As[BM * BK];
    __shared__ __align__(16) u16 Bs[BM * BK];

    const int tid = threadIdx.x;
    const int lane = tid & 63, wid = tid >> 6;
    const int wr = wid >> 1, wc = wid & 1;
    const int col = lane & 15, kg = lane >> 4;

    const int r0 = tid >> 2, ko = (tid & 3) * 8;
    const int rB = tid >> 1, hfB = (tid & 1) * 16;
    const float* p2 = W2 + (size_t)(n0 + rB) * K + hfB;

    f32x4 acc[4][4] = {};

    for (int k0 = 0; k0 < K; k0 += BK) {
        int4 va0 = *(const int4*)(Hm + (size_t)(slot0 + r0) * K + k0 + ko);
        int4 va1 = *(const int4*)(Hm + (size_t)(slot0 + r0 + 64) * K + k0 + ko);
        *(int4*)(As + r0 * BK + ko) = va0;
        *(int4*)(As + (r0 + 64) * BK + ko) = va1;

        float4 a0 = *(const float4*)(p2 + k0);
        float4 a1 = *(const float4*)(p2 + k0 + 4);
        float4 a2 = *(const float4*)(p2 + k0 + 8);
        float4 a3 = *(const float4*)(p2 + k0 + 12);
        *(int4*)(Bs + rB * BK + hfB)     = pack8(a0, a1);
        *(int4*)(Bs + rB * BK + hfB + 8) = pack8(a2, a3);

        __syncthreads();

        short8 a[4];
#pragma unroll
        for (int mi = 0; mi < 4; mi++)
            a[mi] = *(const short8*)(As + (wr * 64 + mi * 16 + col) * BK + kg * 8);
#pragma unroll
        for (int ni = 0; ni < 4; ni++) {
            short8 bv = *(const short8*)(Bs + (wc * 64 + ni * 16 + col) * BK + kg * 8);
#pragma unroll
            for (int mi = 0; mi < 4; mi++)
                acc[mi][ni] = __builtin_amdgcn_mfma_f32_16x16x32_bf16(a[mi], bv, acc[mi][ni], 0, 0, 0);
        }
        __syncthreads();
    }

#pragma unroll
    for (int mi = 0; mi < 4; mi++) {
#pragma unroll
        for (int j = 0; j < 4; j++) {
            int rloc = wr * 64 + mi * 16 + kg * 4 + j;
            int slot = slot0 + rloc;
            if (ATOMIC) {
                int token = perm[slot];
                if (token < 0) continue;
                float w = pw[slot];
#pragma unroll
                for (int ni = 0; ni < 4; ni++) {
                    int c = n0 + wc * 64 + ni * 16 + col;
                    atomicAdd(&Out[(size_t)token * DIM_ + c], acc[mi][ni][j] * w);
                }
            } else {
#pragma unroll
                for (int ni = 0; ni < 4; ni++) {
                    int c = n0 + wc * 64 + ni * 16 + col;
                    Out[(size_t)slot * DIM_ + c] = acc[mi][ni][j];
                }
            }
        }
    }
}

// ---------------- launch ----------------

extern "C" void kernel_launch(void* const* d_in, const int* in_sizes, int n_in,
                              void* d_out, int out_size, void* d_ws, size_t ws_size,
                              hipStream_t stream) {
    (void)in_sizes; (void)n_in; (void)out_size; (void)ws_size;
    const float* x   = (const float*)d_in[0];
    const float* gw  = (const float*)d_in[1];
    const float* w1  = (const float*)d_in[2];
    const float* w2  = (const float*)d_in[3];
    const float* w3  = (const float*)d_in[4];
    const float* sw1 = (const float*)d_in[5];
    const float* sw2 = (const float*)d_in[6];
    const float* sw3 = (const float*)d_in[7];
    float* out = (float*)d_out;

    char* ws = (char*)d_ws;
    size_t off = 0;
    auto take = [&](size_t bytes) -> void* {
        void* p = ws + off;
        off += (bytes + 255) & ~(size_t)255;
        return p;
    };
    u16*   xb      = (u16*)take((size_t)TTOK * DIM_ * 2);
    u16*   hbuf    = (u16*)take((size_t)MAXROWS * INTER_ * 2);  // also reused for shared h (11.5M < 14.4M elems)
    int*   perm_rt = (int*)take((size_t)MAXROWS * 4);
    float* pw_rt   = (float*)take((size_t)MAXROWS * 4);
    int*   perm_sh = (int*)take((size_t)TTOK * 4);
    int*   topi    = (int*)take((size_t)TTOK * 2 * 4);
    float* topw    = (float*)take((size_t)TTOK * 2 * 4);
    int*   misc    = (int*)take(1024);

    init_kernel<<<MAXROWS / 256, 256, 0, stream>>>(perm_rt, pw_rt, perm_sh, misc);
    convert_x_kernel<<<(TTOK * DIM_ / 4) / 256, 256, 0, stream>>>(x, xb);
    gate_kernel<<<TTOK, 64, 0, stream>>>(x, gw, topi, topw, misc);
    scan_kernel<<<1, 1, 0, stream>>>(misc);
    scatter_kernel<<<TTOK / 256, 256, 0, stream>>>(topi, topw, misc, perm_rt, pw_rt);

    // shared expert: h_sh = silu(x@sw1^T)*(x@sw3^T) ; out = h_sh @ sw2^T (plain store, inits out)
    gemm_h13_k<false><<<dim3(TTOK / BM, SINTER_ / BN), 256, 0, stream>>>(
        xb, sw1, sw3, hbuf, perm_sh, nullptr, nullptr, SINTER_, DIM_);
    gemm_out_k<false><<<dim3(TTOK / BM, DIM_ / BN), 256, 0, stream>>>(
        hbuf, sw2, out, nullptr, nullptr, nullptr, nullptr, SINTER_);

    // routed experts (grouped over padded slot tiles), atomicAdd combine
    gemm_h13_k<true><<<dim3(MAXMT, INTER_ / BN), 256, 0, stream>>>(
        xb, w1, w3, hbuf, perm_rt, misc + 48, misc + 128, INTER_, DIM_);
    gemm_out_k<true><<<dim3(MAXMT, DIM_ / BN), 256, 0, stream>>>(
        hbuf, w2, out, perm_rt, pw_rt, misc + 48, misc + 128, INTER_);
}

// Round 3
// 868.684 us; speedup vs baseline: 1.1384x; 1.1384x over previous
//
#include <hip/hip_runtime.h>
#include <hip/hip_bf16.h>
#include <cstdint>
#include <cstddef>

#define TTOK   4096
#define DIM_   2048
#define INTER_ 1408
#define NEXP   16
#define SINTER_ 2816
#define BM 128
#define BN 128
#define BK 32
#define MAXROWS (TTOK*2 + NEXP*BM)      /* 10240 padded routed slots */
#define MAXMT   (TTOK*2/BM + NEXP)      /* 80 worst-case M tiles */

typedef unsigned short u16;
typedef __attribute__((ext_vector_type(8))) short short8;
typedef __attribute__((ext_vector_type(4))) float f32x4;

__device__ __forceinline__ u16 f2bf(float f) {
    __hip_bfloat16 h = __float2bfloat16(f);
    union { __hip_bfloat16 h; u16 u; } c; c.h = h; return c.u;
}

__device__ __forceinline__ unsigned pk2(float a, float b) {
    unsigned r;
    asm("v_cvt_pk_bf16_f32 %0, %1, %2" : "=v"(r) : "v"(a), "v"(b));
    return r;
}

__device__ __forceinline__ int4 pack8(float4 a, float4 b) {
    int4 r;
    r.x = (int)pk2(a.x, a.y);
    r.y = (int)pk2(a.z, a.w);
    r.z = (int)pk2(b.x, b.y);
    r.w = (int)pk2(b.z, b.w);
    return r;
}

// ---------------- small kernels ----------------

// misc layout (ints): [0..16) counts, [16..32) fill, [32..48) base,
//                     [48..128) tile_expert, [128..208) tile_row0
__global__ void init_kernel(int* perm_rt, float* pw_rt, int* perm_sh, int* misc) {
    int i = blockIdx.x * 256 + threadIdx.x;
    if (i < MAXROWS) { perm_rt[i] = -1; pw_rt[i] = 0.f; }
    if (i < TTOK)    perm_sh[i] = i;
    if (i < 32)      misc[i] = 0;
}

__global__ void convert_x_kernel(const float* __restrict__ x, u16* __restrict__ xb) {
    size_t i = (size_t)blockIdx.x * 256 + threadIdx.x;   // covers TTOK*DIM_/4
    float4 v = *(const float4*)(x + i * 4);
    uint2 o;
    o.x = pk2(v.x, v.y);
    o.y = pk2(v.z, v.w);
    *(uint2*)(xb + i * 4) = o;
}

__global__ void gate_kernel(const float* __restrict__ x, const float* __restrict__ gw,
                            int* __restrict__ topi, float* __restrict__ topw,
                            int* __restrict__ misc) {
    int t = blockIdx.x;
    int lane = threadIdx.x;
    const float* xr = x + (size_t)t * DIM_;
    float acc[NEXP];
#pragma unroll
    for (int e = 0; e < NEXP; e++) acc[e] = 0.f;
#pragma unroll
    for (int i = 0; i < 8; i++) {
        int k = i * 256 + lane * 4;
        float4 xv = *(const float4*)(xr + k);
#pragma unroll
        for (int e = 0; e < NEXP; e++) {
            float4 gv = *(const float4*)(gw + (size_t)e * DIM_ + k);
            acc[e] += xv.x * gv.x + xv.y * gv.y + xv.z * gv.z + xv.w * gv.w;
        }
    }
#pragma unroll
    for (int e = 0; e < NEXP; e++) {
        float v = acc[e];
        for (int off = 32; off > 0; off >>= 1) v += __shfl_down(v, off);
        acc[e] = v;   // lane 0 has the full dot
    }
    if (lane == 0) {
        float m = acc[0];
#pragma unroll
        for (int e = 1; e < NEXP; e++) m = fmaxf(m, acc[e]);
        float p[NEXP]; float s = 0.f;
#pragma unroll
        for (int e = 0; e < NEXP; e++) { p[e] = __expf(acc[e] - m); s += p[e]; }
        int i0 = 0; float v0 = p[0];
#pragma unroll
        for (int e = 1; e < NEXP; e++) if (p[e] > v0) { v0 = p[e]; i0 = e; }
        int i1 = -1; float v1 = -1.f;
#pragma unroll
        for (int e = 0; e < NEXP; e++) if (e != i0 && p[e] > v1) { v1 = p[e]; i1 = e; }
        float inv = 1.f / s;
        topi[2 * t] = i0; topi[2 * t + 1] = i1;
        topw[2 * t] = v0 * inv; topw[2 * t + 1] = v1 * inv;
        atomicAdd(&misc[i0], 1);
        atomicAdd(&misc[i1], 1);
    }
}

__global__ void scan_kernel(int* misc) {
    int* counts = misc;
    int* base   = misc + 32;
    int* te     = misc + 48;
    int* tr     = misc + 128;
    int b = 0, tt = 0;
    for (int e = 0; e < NEXP; e++) {
        int c = counts[e];
        int nt = (c + BM - 1) >> 7;
        base[e] = b;
        for (int i = 0; i < nt; i++) { te[tt] = e; tr[tt] = b + i * BM; tt++; }
        b += nt * BM;
    }
    for (int i = tt; i < MAXMT; i++) te[i] = -1;
}

__global__ void scatter_kernel(const int* __restrict__ topi, const float* __restrict__ topw,
                               int* __restrict__ misc, int* __restrict__ perm,
                               float* __restrict__ pw) {
    int t = blockIdx.x * 256 + threadIdx.x;
    if (t >= TTOK) return;
    int* fill = misc + 16;
    int* base = misc + 32;
#pragma unroll
    for (int k = 0; k < 2; k++) {
        int e = topi[2 * t + k];
        int pos = base[e] + atomicAdd(&fill[e], 1);
        perm[pos] = t;
        pw[pos] = topw[2 * t + k];
    }
}

// ---------------- GEMM kernels ----------------
// C[M,N] = A[M,K] @ B[N,K]^T ; A bf16, B f32 (cvt_pk while staging).
// 128x128 tile, BK=32, 4 waves (2x2 of 64x64), mfma_f32_16x16x32_bf16.
// XCD-chunked 1D grid: xcd = bid&7, q = xcd*chunk + (bid>>3); q is jn-major so
// all M-tiles sharing a weight panel are consecutive q's on ONE XCD (T1).
// Reg-prefetch: next K-tile's global loads issue between barrier and MFMA (T14).

template<bool GROUPED>
__global__ __launch_bounds__(256, 2) void gemm_h13_k(
    const u16* __restrict__ Xb,
    const float* __restrict__ W1b, const float* __restrict__ W3b,
    u16* __restrict__ H,
    const int* __restrict__ perm,
    const int* __restrict__ te, const int* __restrict__ tr,
    int N, int K, int nt_m, int chunk)
{
    const int q = (blockIdx.x & 7) * chunk + (blockIdx.x >> 3);
    if (q >= nt_m * (N / BN)) return;
    const int jn = q / nt_m, im = q % nt_m;
    int e, slot0;
    if (GROUPED) { e = te[im]; if (e < 0) return; slot0 = tr[im]; }
    else         { e = 0; slot0 = im * BM; }
    const int n0 = jn * BN;
    const float* W1 = W1b + (size_t)e * N * K;
    const float* W3 = W3b + (size_t)e * N * K;

    __shared__ __align__(16) u16 As[BM * BK];
    __shared__ __align__(16) u16 B1s[BM * BK];
    __shared__ __align__(16) u16 B3s[BM * BK];

    const int tid = threadIdx.x;
    const int lane = tid & 63, wid = tid >> 6;
    const int wr = wid >> 1, wc = wid & 1;
    const int col = lane & 15, kg = lane >> 4;

    const int r0 = tid >> 2, ko = (tid & 3) * 8;
    const int tok0 = perm[slot0 + r0];
    const int tok1 = perm[slot0 + r0 + 64];
    const u16* pA0 = (tok0 >= 0) ? Xb + (size_t)tok0 * K + ko : nullptr;
    const u16* pA1 = (tok1 >= 0) ? Xb + (size_t)tok1 * K + ko : nullptr;
    const int rB = tid >> 1, hfB = (tid & 1) * 16;
    const float* p1 = W1 + (size_t)(n0 + rB) * K + hfB;
    const float* p3 = W3 + (size_t)(n0 + rB) * K + hfB;

    f32x4 acc1[4][4] = {};
    f32x4 acc3[4][4] = {};

    int4 va0, va1;
    float4 f1[4], f3[4];

    // prologue loads (tile 0)
    va0 = pA0 ? *(const int4*)(pA0) : make_int4(0, 0, 0, 0);
    va1 = pA1 ? *(const int4*)(pA1) : make_int4(0, 0, 0, 0);
#pragma unroll
    for (int i = 0; i < 4; i++) { f1[i] = *(const float4*)(p1 + i * 4); f3[i] = *(const float4*)(p3 + i * 4); }

    for (int k0 = 0; k0 < K; k0 += BK) {
        // stage current tile (regs -> LDS)
        *(int4*)(As + r0 * BK + ko) = va0;
        *(int4*)(As + (r0 + 64) * BK + ko) = va1;
        *(int4*)(B1s + rB * BK + hfB)     = pack8(f1[0], f1[1]);
        *(int4*)(B1s + rB * BK + hfB + 8) = pack8(f1[2], f1[3]);
        *(int4*)(B3s + rB * BK + hfB)     = pack8(f3[0], f3[1]);
        *(int4*)(B3s + rB * BK + hfB + 8) = pack8(f3[2], f3[3]);
        __syncthreads();

        // issue next tile's global loads; they complete under the MFMA phase
        const int kn = k0 + BK;
        if (kn < K) {
            va0 = pA0 ? *(const int4*)(pA0 + kn) : make_int4(0, 0, 0, 0);
            va1 = pA1 ? *(const int4*)(pA1 + kn) : make_int4(0, 0, 0, 0);
#pragma unroll
            for (int i = 0; i < 4; i++) {
                f1[i] = *(const float4*)(p1 + kn + i * 4);
                f3[i] = *(const float4*)(p3 + kn + i * 4);
            }
        }

        short8 a[4];
#pragma unroll
        for (int mi = 0; mi < 4; mi++)
            a[mi] = *(const short8*)(As + (wr * 64 + mi * 16 + col) * BK + kg * 8);
#pragma unroll
        for (int ni = 0; ni < 4; ni++) {
            short8 v1 = *(const short8*)(B1s + (wc * 64 + ni * 16 + col) * BK + kg * 8);
            short8 v3 = *(const short8*)(B3s + (wc * 64 + ni * 16 + col) * BK + kg * 8);
#pragma unroll
            for (int mi = 0; mi < 4; mi++) {
                acc1[mi][ni] = __builtin_amdgcn_mfma_f32_16x16x32_bf16(a[mi], v1, acc1[mi][ni], 0, 0, 0);
                acc3[mi][ni] = __builtin_amdgcn_mfma_f32_16x16x32_bf16(a[mi], v3, acc3[mi][ni], 0, 0, 0);
            }
        }
        __syncthreads();
    }

    // epilogue: h = silu(acc1) * acc3, store bf16 (padding rows produce 0)
#pragma unroll
    for (int mi = 0; mi < 4; mi++) {
#pragma unroll
        for (int j = 0; j < 4; j++) {
            int row = slot0 + wr * 64 + mi * 16 + kg * 4 + j;
#pragma unroll
            for (int ni = 0; ni < 4; ni++) {
                float v1 = acc1[mi][ni][j];
                float v3 = acc3[mi][ni][j];
                float hv = v1 / (1.f + __expf(-v1)) * v3;
                int c = n0 + wc * 64 + ni * 16 + col;
                H[(size_t)row * N + c] = f2bf(hv);
            }
        }
    }
}

template<bool ATOMIC>
__global__ __launch_bounds__(256, 2) void gemm_out_k(
    const u16* __restrict__ Hm,
    const float* __restrict__ W2b,
    float* __restrict__ Out,
    const int* __restrict__ perm, const float* __restrict__ pw,
    const int* __restrict__ te, const int* __restrict__ tr,
    int K, int nt_m, int chunk)
{
    const int q = (blockIdx.x & 7) * chunk + (blockIdx.x >> 3);
    if (q >= nt_m * (DIM_ / BN)) return;
    const int jn = q / nt_m, im = q % nt_m;
    int e, slot0;
    if (ATOMIC) { e = te[im]; if (e < 0) return; slot0 = tr[im]; }
    else        { e = 0; slot0 = im * BM; }
    const int n0 = jn * BN;
    const float* W2 = W2b + (size_t)e * DIM_ * K;

    __shared__ __align__(16) u16 As[BM * BK];
    __shared__ __align__(16) u16 Bs[BM * BK];

    const int tid = threadIdx.x;
    const int lane = tid & 63, wid = tid >> 6;
    const int wr = wid >> 1, wc = wid & 1;
    const int col = lane & 15, kg = lane >> 4;

    const int r0 = tid >> 2, ko = (tid & 3) * 8;
    const int rB = tid >> 1, hfB = (tid & 1) * 16;
    const u16* pA0 = Hm + (size_t)(slot0 + r0) * K + ko;
    const u16* pA1 = Hm + (size_t)(slot0 + r0 + 64) * K + ko;
    const float* p2 = W2 + (size_t)(n0 + rB) * K + hfB;

    f32x4 acc[4][4] = {};

    int4 va0, va1;
    float4 fb[4];
    va0 = *(const int4*)(pA0);
    va1 = *(const int4*)(pA1);
#pragma unroll
    for (int i = 0; i < 4; i++) fb[i] = *(const float4*)(p2 + i * 4);

    for (int k0 = 0; k0 < K; k0 += BK) {
        *(int4*)(As + r0 * BK + ko) = va0;
        *(int4*)(As + (r0 + 64) * BK + ko) = va1;
        *(int4*)(Bs + rB * BK + hfB)     = pack8(fb[0], fb[1]);
        *(int4*)(Bs + rB * BK + hfB + 8) = pack8(fb[2], fb[3]);
        __syncthreads();

        const int kn = k0 + BK;
        if (kn < K) {
            va0 = *(const int4*)(pA0 + kn);
            va1 = *(const int4*)(pA1 + kn);
#pragma unroll
            for (int i = 0; i < 4; i++) fb[i] = *(const float4*)(p2 + kn + i * 4);
        }

        short8 a[4];
#pragma unroll
        for (int mi = 0; mi < 4; mi++)
            a[mi] = *(const short8*)(As + (wr * 64 + mi * 16 + col) * BK + kg * 8);
#pragma unroll
        for (int ni = 0; ni < 4; ni++) {
            short8 bv = *(const short8*)(Bs + (wc * 64 + ni * 16 + col) * BK + kg * 8);
#pragma unroll
            for (int mi = 0; mi < 4; mi++)
                acc[mi][ni] = __builtin_amdgcn_mfma_f32_16x16x32_bf16(a[mi], bv, acc[mi][ni], 0, 0, 0);
        }
        __syncthreads();
    }

#pragma unroll
    for (int mi = 0; mi < 4; mi++) {
#pragma unroll
        for (int j = 0; j < 4; j++) {
            int rloc = wr * 64 + mi * 16 + kg * 4 + j;
            int slot = slot0 + rloc;
            if (ATOMIC) {
                int token = perm[slot];
                if (token < 0) continue;
                float w = pw[slot];
#pragma unroll
                for (int ni = 0; ni < 4; ni++) {
                    int c = n0 + wc * 64 + ni * 16 + col;
                    atomicAdd(&Out[(size_t)token * DIM_ + c], acc[mi][ni][j] * w);
                }
            } else {
#pragma unroll
                for (int ni = 0; ni < 4; ni++) {
                    int c = n0 + wc * 64 + ni * 16 + col;
                    Out[(size_t)slot * DIM_ + c] = acc[mi][ni][j];
                }
            }
        }
    }
}

// ---------------- launch ----------------

extern "C" void kernel_launch(void* const* d_in, const int* in_sizes, int n_in,
                              void* d_out, int out_size, void* d_ws, size_t ws_size,
                              hipStream_t stream) {
    (void)in_sizes; (void)n_in; (void)out_size; (void)ws_size;
    const float* x   = (const float*)d_in[0];
    const float* gw  = (const float*)d_in[1];
    const float* w1  = (const float*)d_in[2];
    const float* w2  = (const float*)d_in[3];
    const float* w3  = (const float*)d_in[4];
    const float* sw1 = (const float*)d_in[5];
    const float* sw2 = (const float*)d_in[6];
    const float* sw3 = (const float*)d_in[7];
    float* out = (float*)d_out;

    char* ws = (char*)d_ws;
    size_t off = 0;
    auto take = [&](size_t bytes) -> void* {
        void* p = ws + off;
        off += (bytes + 255) & ~(size_t)255;
        return p;
    };
    u16*   xb      = (u16*)take((size_t)TTOK * DIM_ * 2);
    u16*   hbuf    = (u16*)take((size_t)MAXROWS * INTER_ * 2);
    int*   perm_rt = (int*)take((size_t)MAXROWS * 4);
    float* pw_rt   = (float*)take((size_t)MAXROWS * 4);
    int*   perm_sh = (int*)take((size_t)TTOK * 4);
    int*   topi    = (int*)take((size_t)TTOK * 2 * 4);
    float* topw    = (float*)take((size_t)TTOK * 2 * 4);
    int*   misc    = (int*)take(1024);

    init_kernel<<<MAXROWS / 256, 256, 0, stream>>>(perm_rt, pw_rt, perm_sh, misc);
    convert_x_kernel<<<(TTOK * DIM_ / 4) / 256, 256, 0, stream>>>(x, xb);
    gate_kernel<<<TTOK, 64, 0, stream>>>(x, gw, topi, topw, misc);
    scan_kernel<<<1, 1, 0, stream>>>(misc);
    scatter_kernel<<<TTOK / 256, 256, 0, stream>>>(topi, topw, misc, perm_rt, pw_rt);

    auto grid8 = [](int total) { return ((total + 7) / 8) * 8; };
    auto chunk8 = [](int total) { return (total + 7) / 8; };

    // shared expert
    {
        int total = (TTOK / BM) * (SINTER_ / BN);
        gemm_h13_k<false><<<grid8(total), 256, 0, stream>>>(
            xb, sw1, sw3, hbuf, perm_sh, nullptr, nullptr, SINTER_, DIM_, TTOK / BM, chunk8(total));
    }
    {
        int total = (TTOK / BM) * (DIM_ / BN);
        gemm_out_k<false><<<grid8(total), 256, 0, stream>>>(
            hbuf, sw2, out, nullptr, nullptr, nullptr, nullptr, SINTER_, TTOK / BM, chunk8(total));
    }
    // routed experts
    {
        int total = MAXMT * (INTER_ / BN);
        gemm_h13_k<true><<<grid8(total), 256, 0, stream>>>(
            xb, w1, w3, hbuf, perm_rt, misc + 48, misc + 128, INTER_, DIM_, MAXMT, chunk8(total));
    }
    {
        int total = MAXMT * (DIM_ / BN);
        gemm_out_k<true><<<grid8(total), 256, 0, stream>>>(
            hbuf, w2, out, perm_rt, pw_rt, misc + 48, misc + 128, INTER_, MAXMT, chunk8(total));
    }
}